// Round 12
// baseline (397.605 us; speedup 1.0000x reference)
//
#include <hip/hip_runtime.h>
#include <stdint.h>

#define N_NODES 50000
#define N_EDGES 800000
#define D 512
#define M_PAD 50048    // 391 * 128
#define CAP 64         // bucket slots per node; Poisson(16) overflow ~1e-18
#define CAPSH 6

// k_mega block-role ranges (256 threads each)
#define FILL_NB 3125   // 3125*256 = 800000 exact
#define WT_NB   1024   // 1024 blocks: wt row = bid>>1, half-row per block
#define GEMM_NB 1564   // 391 * 4 tiles (128x128)

typedef __attribute__((ext_vector_type(8))) __bf16 bf16x8;
typedef __attribute__((ext_vector_type(8))) unsigned short u16x8;
typedef __attribute__((ext_vector_type(4))) float f32x4;

static __device__ __forceinline__ unsigned short f2bf(float f) {
  unsigned u = __float_as_uint(f);
  u += 0x7fff + ((u >> 16) & 1);   // round-to-nearest-even
  return (unsigned short)(u >> 16);
}
static __device__ __forceinline__ float bf2f(unsigned short h) {
  return __uint_as_float(((unsigned)h) << 16);
}

// async global->LDS, 16B per lane; LDS base must be wave-uniform (lane-linear fill)
static __device__ __forceinline__ void gload_lds16(const void* g, void* l) {
  __builtin_amdgcn_global_load_lds((const __attribute__((address_space(1))) unsigned*)g,
                                   (__attribute__((address_space(3))) unsigned*)l, 16, 0, 0);
}

// ---- fused: edge-bucket fill (atomic, latency-bound) + W transpose-cast ----
// X-cast has been fused into k_gemm's A-staging; k_mega is now fill-dominated.
__global__ __launch_bounds__(256) void k_mega(const float* __restrict__ w,
                                              const float* __restrict__ ew,
                                              const int* __restrict__ esrc,
                                              const int* __restrict__ edst,
                                              unsigned short* __restrict__ wt,
                                              int* __restrict__ cur,
                                              int2* __restrict__ cew) {
  int bid = blockIdx.x;
  if (bid < FILL_NB) {
    int e = bid * 256 + threadIdx.x;   // e < 800000 always (exact grid)
    int d = edst[e];
    int r = atomicAdd(&cur[d], 1);
    if (r < CAP) cew[(d << CAPSH) + r] = make_int2(esrc[e], __float_as_int(ew[e]));
    return;
  }
  bid -= FILL_NB;
  // W transpose-cast: coalesced write, strided read (W is 1MB, L2-resident)
  int n = bid >> 1;                          // wt row
  int k = ((bid & 1) << 8) + threadIdx.x;    // coalesced write along wt row
  wt[n * D + k] = f2bf(w[k * D + n]);
}

// ---- bf16 GEMM with FUSED A-cast: C[M_PAD x D] = cast(X) * Wt^T, 128x128 tile, BK=64.
// A: reg-staged from fp32 X (global_load_dwordx4 x2 -> f2bf x8 -> swizzled ds_write_b128).
// B: global_load_lds from bf16 Wt (pre-swizzled source).
// 8-slot XOR chunk-swizzle on both LDS tiles (conflict-free ds_read_b128);
// bijective XCD-chunked block swizzle (A panel L2-shared by its 4 bn-tiles).
__global__ __launch_bounds__(256) void k_gemm(const float* __restrict__ X,
                                              const unsigned short* __restrict__ Bt,
                                              unsigned short* __restrict__ C) {
  __shared__ unsigned short lds_a[128 * 64];   // 16 KB
  __shared__ unsigned short lds_b[128 * 64];   // 16 KB

  // bijective chunked XCD swizzle (m204): 1564 = 8*195 + 4
  const int orig = blockIdx.x;
  const int q = GEMM_NB / 8, rq = GEMM_NB % 8;
  const int xcd = orig & 7, jj0 = orig >> 3;
  const int wgid = (xcd < rq ? xcd * (q + 1) : rq * (q + 1) + (xcd - rq) * q) + jj0;
  const int bm = wgid >> 2, bn = wgid & 3;

  const int tid  = threadIdx.x;
  const int m0   = bm * 128, n0 = bn * 128;
  const int wave = tid >> 6, lane = tid & 63;
  const int wm   = wave & 1, wn = wave >> 1;
  const int l15  = lane & 15, quad = lane >> 4;

  f32x4 acc[4][4];
#pragma unroll
  for (int i = 0; i < 4; i++)
#pragma unroll
    for (int j = 0; j < 4; j++) acc[i][j] = f32x4{0.f, 0.f, 0.f, 0.f};

  for (int kt = 0; kt < D / 64; ++kt) {        // 8 K-steps
    const int k0 = kt * 64;
    __syncthreads();
#pragma unroll
    for (int c = 0; c < 4; c++) {
      int i = c * 256 + wave * 64 + lane;      // 16B chunk id, 1024 chunks/matrix
      int r = i >> 3, s = i & 7;
      int g = s ^ (r & 7);                     // chunk that belongs in slot s of row r
      // B: async to LDS (bf16 source)
      gload_lds16(&Bt[(long long)(n0 + r) * D + k0 + (g << 3)], &lds_b[(c * 256 + wave * 64) * 8]);
      // A: fused fp32->bf16 reg-staging (row guard: X has exactly N_NODES rows)
      int arow = m0 + r;
      u16x8 val = {0, 0, 0, 0, 0, 0, 0, 0};
      if (arow < N_NODES) {
        const float* src = X + (long long)arow * D + k0 + (g << 3);
        float4 lo = *(const float4*)src;
        float4 hi = *(const float4*)(src + 4);
        val[0] = f2bf(lo.x); val[1] = f2bf(lo.y); val[2] = f2bf(lo.z); val[3] = f2bf(lo.w);
        val[4] = f2bf(hi.x); val[5] = f2bf(hi.y); val[6] = f2bf(hi.z); val[7] = f2bf(hi.w);
      }
      *(u16x8*)&lds_a[(c * 256 + wave * 64 + lane) * 8] = val;
    }
    __syncthreads();
#pragma unroll
    for (int kk = 0; kk < 2; kk++) {
      bf16x8 af[4], bfr[4];
#pragma unroll
      for (int t = 0; t < 4; t++) {
        int ra = wm * 64 + t * 16 + l15;
        int rb = wn * 64 + t * 16 + l15;
        af[t]  = *(const bf16x8*)&lds_a[ra * 64 + ((((kk << 2) + quad) ^ (ra & 7)) << 3)];
        bfr[t] = *(const bf16x8*)&lds_b[rb * 64 + ((((kk << 2) + quad) ^ (rb & 7)) << 3)];
      }
#pragma unroll
      for (int i = 0; i < 4; i++)
#pragma unroll
        for (int j = 0; j < 4; j++)
          acc[i][j] = __builtin_amdgcn_mfma_f32_16x16x32_bf16(af[i], bfr[j], acc[i][j], 0, 0, 0);
    }
  }

#pragma unroll
  for (int i = 0; i < 4; i++)
#pragma unroll
    for (int j = 0; j < 4; j++)
#pragma unroll
      for (int r = 0; r < 4; r++) {
        int row = m0 + wm * 64 + i * 16 + quad * 4 + r;
        int col = n0 + wn * 64 + j * 16 + l15;
        C[(long long)row * D + col] = f2bf(acc[i][j][r]);
      }
}

// ---- aggregate: one BLOCK per node, bucket CSR (pattern-bound at ~115 us) ----
__global__ __launch_bounds__(256) void k_agg(const int* __restrict__ cur,
                                             const int2* __restrict__ cew,
                                             const unsigned short* __restrict__ S,
                                             float* __restrict__ out) {
  __shared__ float s_part[4 * 512];
  const int node  = blockIdx.x;
  int cnt = cur[node];
  cnt = (cnt > CAP) ? CAP : cnt;             // memory-safety clamp (P(overflow)~1e-18)
  const int start = node << CAPSH, end = start + cnt;
  const int wave  = threadIdx.x >> 6, lane = threadIdx.x & 63;
  float a[8];
#pragma unroll
  for (int k = 0; k < 8; k++) a[k] = 0.f;

#define EDGE_FMA(V, W)                                             \
  do {                                                             \
    a[0] = fmaf(W, bf2f((unsigned short)(V.x & 0xffffu)), a[0]);   \
    a[1] = fmaf(W, bf2f((unsigned short)(V.x >> 16)),     a[1]);   \
    a[2] = fmaf(W, bf2f((unsigned short)(V.y & 0xffffu)), a[2]);   \
    a[3] = fmaf(W, bf2f((unsigned short)(V.y >> 16)),     a[3]);   \
    a[4] = fmaf(W, bf2f((unsigned short)(V.z & 0xffffu)), a[4]);   \
    a[5] = fmaf(W, bf2f((unsigned short)(V.z >> 16)),     a[5]);   \
    a[6] = fmaf(W, bf2f((unsigned short)(V.w & 0xffffu)), a[6]);   \
    a[7] = fmaf(W, bf2f((unsigned short)(V.w >> 16)),     a[7]);   \
  } while (0)

#define GATHER(P) (*(const uint4*)(S + (size_t)(P).x * D + lane * 8))

  int e = start + wave;
  // 2-deep pipelined pairs across 4 waves (8 rows in flight per block)
  for (; e + 4 < end; e += 8) {
    int2 p0 = cew[e], p1 = cew[e + 4];
    uint4 v0 = GATHER(p0);
    uint4 v1 = GATHER(p1);
    EDGE_FMA(v0, __int_as_float(p0.y));
    EDGE_FMA(v1, __int_as_float(p1.y));
  }
  if (e < end) {
    int2 p0 = cew[e];
    uint4 v0 = GATHER(p0);
    EDGE_FMA(v0, __int_as_float(p0.y));
  }
#undef GATHER
#undef EDGE_FMA

  // cross-wave combine
  float4* sp = (float4*)&s_part[wave * 512 + lane * 8];
  sp[0] = make_float4(a[0], a[1], a[2], a[3]);
  sp[1] = make_float4(a[4], a[5], a[6], a[7]);
  __syncthreads();
  int col = threadIdx.x * 2;
  float2 r0 = *(const float2*)&s_part[0 * 512 + col];
  float2 r1 = *(const float2*)&s_part[1 * 512 + col];
  float2 r2 = *(const float2*)&s_part[2 * 512 + col];
  float2 r3 = *(const float2*)&s_part[3 * 512 + col];
  float2 res = make_float2(r0.x + r1.x + r2.x + r3.x, r0.y + r1.y + r2.y + r3.y);
  // non-temporal 8B store (out never re-read; keep L2/L3 for S)
  typedef __attribute__((ext_vector_type(2))) float f32x2;
  f32x2 rv = {res.x, res.y};
  __builtin_nontemporal_store(rv, (f32x2*)(out + (size_t)node * D + col));
}

extern "C" void kernel_launch(void* const* d_in, const int* in_sizes, int n_in,
                              void* d_out, int out_size, void* d_ws, size_t ws_size,
                              hipStream_t stream) {
  const float* x    = (const float*)d_in[0];
  const float* w    = (const float*)d_in[1];
  const float* ew   = (const float*)d_in[2];
  const int*   esrc = (const int*)d_in[3];
  const int*   edst = (const int*)d_in[4];
  float* out = (float*)d_out;

  char* p = (char*)d_ws;
  auto align256 = [](size_t v) { return (v + 255) & ~(size_t)255; };
  unsigned short* sb = (unsigned short*)p;  p += align256((size_t)M_PAD * D * 2);
  unsigned short* wt = (unsigned short*)p;  p += align256((size_t)D * D * 2);
  int*   cur  = (int*)p;   p += align256((size_t)N_NODES * 4);
  int2*  cew  = (int2*)p;  p += align256((size_t)N_NODES * CAP * 8);

  // bucket counters must be zero before the fill blocks run
  hipMemsetAsync(cur, 0, (size_t)N_NODES * 4, stream);
  // fused: bucket-fill (atomic placement) + W^T cast   (X-cast now lives in k_gemm)
  k_mega<<<FILL_NB + WT_NB, 256, 0, stream>>>(w, ew, esrc, edst, wt, cur, cew);
  // support = cast(X) @ W  (bf16 MFMA; fused A-cast reg-staging, swizzled LDS, XCD blocks)
  k_gemm<<<GEMM_NB, 256, 0, stream>>>(x, wt, sb);
  // aggregate: one block per node, fixed-capacity bucket CSR
  k_agg<<<N_NODES, 256, 0, stream>>>(cur, cew, sb, out);
}

// Round 13
// 369.054 us; speedup vs baseline: 1.0774x; 1.0774x over previous
//
#include <hip/hip_runtime.h>
#include <stdint.h>

#define N_NODES 50000
#define N_EDGES 800000
#define D 512
#define M_PAD 50048    // 391 * 128
#define CAP 64         // bucket slots per node; Poisson(16) overflow ~1e-18
#define CAPSH 6

#define WT_NB   1024   // 1024 blocks: wt row = bid>>1, half-row per block
#define CVT_NB  25024  // 25024*256*4 = M_PAD*D exact
#define GEMM_NB 1564   // 391 * 4 tiles (128x128)
#define FILL_NB 3125   // 3125*256 = 800000 exact

typedef __attribute__((ext_vector_type(8))) __bf16 bf16x8;
typedef __attribute__((ext_vector_type(4))) float f32x4;

static __device__ __forceinline__ unsigned short f2bf(float f) {
  unsigned u = __float_as_uint(f);
  u += 0x7fff + ((u >> 16) & 1);   // round-to-nearest-even
  return (unsigned short)(u >> 16);
}
static __device__ __forceinline__ float bf2f(unsigned short h) {
  return __uint_as_float(((unsigned)h) << 16);
}

// async global->LDS, 16B per lane; LDS base must be wave-uniform (lane-linear fill)
static __device__ __forceinline__ void gload_lds16(const void* g, void* l) {
  __builtin_amdgcn_global_load_lds((const __attribute__((address_space(1))) unsigned*)g,
                                   (__attribute__((address_space(3))) unsigned*)l, 16, 0, 0);
}

// ---- pre-pass: W transpose-cast + X cast (pure bandwidth, no atomics) ----
__global__ __launch_bounds__(256) void k_pre(const float* __restrict__ x,
                                             const float* __restrict__ w,
                                             unsigned short* __restrict__ xb,
                                             unsigned short* __restrict__ wt) {
  int bid = blockIdx.x;
  if (bid < WT_NB) {
    int n = bid >> 1;                          // wt row
    int k = ((bid & 1) << 8) + threadIdx.x;    // coalesced write along wt row
    wt[n * D + k] = f2bf(w[k * D + n]);        // strided read; W is 1MB, L2-resident
    return;
  }
  bid -= WT_NB;
  // X cast: fp32 -> bf16, zero-pad rows [N_NODES, M_PAD)
  long long base = ((long long)bid * 256 + threadIdx.x) * 4;
  int row = (int)(base >> 9);  // D = 512
  ushort4 o;
  if (row < N_NODES) {
    float4 v = *(const float4*)(x + base);
    o.x = f2bf(v.x); o.y = f2bf(v.y); o.z = f2bf(v.z); o.w = f2bf(v.w);
  } else {
    o.x = 0; o.y = 0; o.z = 0; o.w = 0;
  }
  *(ushort4*)(xb + base) = o;
}

// ---- fused: GEMM tiles FIRST, edge-bucket fill LAST.
// gemm needs only xb/wt (from k_pre); fill output (cur/cew) is needed only by k_agg.
// gemm-first => gemm starts immediately; fill blocks flow into freed CU slots and their
// atomic latency hides under remaining MFMA work; only the fill tail is exposed.
// GEMM: 128x128 tile, BK=64, 8-slot XOR chunk-swizzle (pre-swizzled global source +
// swizzled ds_read, conflict-free), bijective XCD-chunked block swizzle.
__global__ __launch_bounds__(256) void k_gf(const unsigned short* __restrict__ A,
                                            const unsigned short* __restrict__ Bt,
                                            unsigned short* __restrict__ C,
                                            const float* __restrict__ ew,
                                            const int* __restrict__ esrc,
                                            const int* __restrict__ edst,
                                            int* __restrict__ cur,
                                            int2* __restrict__ cew) {
  __shared__ unsigned short lds_a[128 * 64];   // 16 KB
  __shared__ unsigned short lds_b[128 * 64];   // 16 KB

  if (blockIdx.x >= GEMM_NB) {   // ---- fill blocks (dispatched after all gemm tiles)
    int e = (blockIdx.x - GEMM_NB) * 256 + threadIdx.x;   // e < 800000 exact
    int d = edst[e];
    int r = atomicAdd(&cur[d], 1);
    if (r < CAP) cew[(d << CAPSH) + r] = make_int2(esrc[e], __float_as_int(ew[e]));
    return;
  }

  // bijective chunked XCD swizzle (m204): 1564 = 8*195 + 4
  const int orig = blockIdx.x;
  const int q = GEMM_NB / 8, rq = GEMM_NB % 8;
  const int xcd = orig & 7, jj0 = orig >> 3;
  const int wgid = (xcd < rq ? xcd * (q + 1) : rq * (q + 1) + (xcd - rq) * q) + jj0;
  const int bm = wgid >> 2, bn = wgid & 3;

  const int tid  = threadIdx.x;
  const int m0   = bm * 128, n0 = bn * 128;
  const int wave = tid >> 6, lane = tid & 63;
  const int wm   = wave & 1, wn = wave >> 1;
  const int l15  = lane & 15, quad = lane >> 4;

  f32x4 acc[4][4];
#pragma unroll
  for (int i = 0; i < 4; i++)
#pragma unroll
    for (int j = 0; j < 4; j++) acc[i][j] = f32x4{0.f, 0.f, 0.f, 0.f};

  for (int kt = 0; kt < D / 64; ++kt) {        // 8 K-steps
    const int k0 = kt * 64;
    __syncthreads();
#pragma unroll
    for (int c = 0; c < 4; c++) {
      int i = c * 256 + wave * 64 + lane;      // 16B chunk id, 1024 chunks/matrix
      int r = i >> 3, s = i & 7;
      int g = s ^ (r & 7);                     // chunk that belongs in slot s of row r
      gload_lds16(&A[(long long)(m0 + r) * D + k0 + (g << 3)], &lds_a[(c * 256 + wave * 64) * 8]);
      gload_lds16(&Bt[(long long)(n0 + r) * D + k0 + (g << 3)], &lds_b[(c * 256 + wave * 64) * 8]);
    }
    __syncthreads();
#pragma unroll
    for (int kk = 0; kk < 2; kk++) {
      bf16x8 af[4], bfr[4];
#pragma unroll
      for (int t = 0; t < 4; t++) {
        int ra = wm * 64 + t * 16 + l15;
        int rb = wn * 64 + t * 16 + l15;
        af[t]  = *(const bf16x8*)&lds_a[ra * 64 + ((((kk << 2) + quad) ^ (ra & 7)) << 3)];
        bfr[t] = *(const bf16x8*)&lds_b[rb * 64 + ((((kk << 2) + quad) ^ (rb & 7)) << 3)];
      }
#pragma unroll
      for (int i = 0; i < 4; i++)
#pragma unroll
        for (int j = 0; j < 4; j++)
          acc[i][j] = __builtin_amdgcn_mfma_f32_16x16x32_bf16(af[i], bfr[j], acc[i][j], 0, 0, 0);
    }
  }

#pragma unroll
  for (int i = 0; i < 4; i++)
#pragma unroll
    for (int j = 0; j < 4; j++)
#pragma unroll
      for (int r = 0; r < 4; r++) {
        int row = m0 + wm * 64 + i * 16 + quad * 4 + r;
        int col = n0 + wn * 64 + j * 16 + l15;
        C[(long long)row * D + col] = f2bf(acc[i][j][r]);
      }
}

// ---- aggregate: one BLOCK per node, bucket CSR (pattern-bound at ~115 us) ----
__global__ __launch_bounds__(256) void k_agg(const int* __restrict__ cur,
                                             const int2* __restrict__ cew,
                                             const unsigned short* __restrict__ S,
                                             float* __restrict__ out) {
  __shared__ float s_part[4 * 512];
  const int node  = blockIdx.x;
  int cnt = cur[node];
  cnt = (cnt > CAP) ? CAP : cnt;             // memory-safety clamp (P(overflow)~1e-18)
  const int start = node << CAPSH, end = start + cnt;
  const int wave  = threadIdx.x >> 6, lane = threadIdx.x & 63;
  float a[8];
#pragma unroll
  for (int k = 0; k < 8; k++) a[k] = 0.f;

#define EDGE_FMA(V, W)                                             \
  do {                                                             \
    a[0] = fmaf(W, bf2f((unsigned short)(V.x & 0xffffu)), a[0]);   \
    a[1] = fmaf(W, bf2f((unsigned short)(V.x >> 16)),     a[1]);   \
    a[2] = fmaf(W, bf2f((unsigned short)(V.y & 0xffffu)), a[2]);   \
    a[3] = fmaf(W, bf2f((unsigned short)(V.y >> 16)),     a[3]);   \
    a[4] = fmaf(W, bf2f((unsigned short)(V.z & 0xffffu)), a[4]);   \
    a[5] = fmaf(W, bf2f((unsigned short)(V.z >> 16)),     a[5]);   \
    a[6] = fmaf(W, bf2f((unsigned short)(V.w & 0xffffu)), a[6]);   \
    a[7] = fmaf(W, bf2f((unsigned short)(V.w >> 16)),     a[7]);   \
  } while (0)

#define GATHER(P) (*(const uint4*)(S + (size_t)(P).x * D + lane * 8))

  int e = start + wave;
  // 2-deep pipelined pairs across 4 waves (8 rows in flight per block)
  for (; e + 4 < end; e += 8) {
    int2 p0 = cew[e], p1 = cew[e + 4];
    uint4 v0 = GATHER(p0);
    uint4 v1 = GATHER(p1);
    EDGE_FMA(v0, __int_as_float(p0.y));
    EDGE_FMA(v1, __int_as_float(p1.y));
  }
  if (e < end) {
    int2 p0 = cew[e];
    uint4 v0 = GATHER(p0);
    EDGE_FMA(v0, __int_as_float(p0.y));
  }
#undef GATHER
#undef EDGE_FMA

  // cross-wave combine
  float4* sp = (float4*)&s_part[wave * 512 + lane * 8];
  sp[0] = make_float4(a[0], a[1], a[2], a[3]);
  sp[1] = make_float4(a[4], a[5], a[6], a[7]);
  __syncthreads();
  int col = threadIdx.x * 2;
  float2 r0 = *(const float2*)&s_part[0 * 512 + col];
  float2 r1 = *(const float2*)&s_part[1 * 512 + col];
  float2 r2 = *(const float2*)&s_part[2 * 512 + col];
  float2 r3 = *(const float2*)&s_part[3 * 512 + col];
  float2 res = make_float2(r0.x + r1.x + r2.x + r3.x, r0.y + r1.y + r2.y + r3.y);
  // non-temporal 8B store (out never re-read; keep L2/L3 for S)
  typedef __attribute__((ext_vector_type(2))) float f32x2;
  f32x2 rv = {res.x, res.y};
  __builtin_nontemporal_store(rv, (f32x2*)(out + (size_t)node * D + col));
}

extern "C" void kernel_launch(void* const* d_in, const int* in_sizes, int n_in,
                              void* d_out, int out_size, void* d_ws, size_t ws_size,
                              hipStream_t stream) {
  const float* x    = (const float*)d_in[0];
  const float* w    = (const float*)d_in[1];
  const float* ew   = (const float*)d_in[2];
  const int*   esrc = (const int*)d_in[3];
  const int*   edst = (const int*)d_in[4];
  float* out = (float*)d_out;

  char* p = (char*)d_ws;
  auto align256 = [](size_t v) { return (v + 255) & ~(size_t)255; };
  unsigned short* xb = (unsigned short*)p;  p += align256((size_t)M_PAD * D * 2);
  unsigned short* sb = (unsigned short*)p;  p += align256((size_t)M_PAD * D * 2);
  unsigned short* wt = (unsigned short*)p;  p += align256((size_t)D * D * 2);
  int*   cur  = (int*)p;   p += align256((size_t)N_NODES * 4);
  int2*  cew  = (int2*)p;  p += align256((size_t)N_NODES * CAP * 8);

  // bucket counters must be zero before the fill blocks in k_gf
  hipMemsetAsync(cur, 0, (size_t)N_NODES * 4, stream);
  // pre-pass: W^T cast + X cast (pure bandwidth)
  k_pre<<<WT_NB + CVT_NB, 256, 0, stream>>>(x, w, xb, wt);
  // fused: GEMM tiles first, fill blocks last (fill atomics hide under MFMA)
  k_gf<<<GEMM_NB + FILL_NB, 256, 0, stream>>>(xb, wt, sb, ew, esrc, edst, cur, cew);
  // aggregate: one block per node, fixed-capacity bucket CSR
  k_agg<<<N_NODES, 256, 0, stream>>>(cur, cew, sb, out);
}

// Round 14
// 350.668 us; speedup vs baseline: 1.1339x; 1.0524x over previous
//
#include <hip/hip_runtime.h>
#include <stdint.h>

#define N_NODES 50000
#define N_EDGES 800000
#define D 512
#define M_PAD 50048    // 391 * 128
#define CAP 64         // bucket slots per node; Poisson(16) overflow ~1e-18
#define CAPSH 6

#define WT_NB   1024   // wt row = bid>>1, half-row per block; also zeroes cur
#define GEMM_NB 1564   // 391 * 4 tiles (128x128)
#define FILL_NB 3125   // 3125*256 = 800000 exact

typedef __attribute__((ext_vector_type(8))) __bf16 bf16x8;
typedef __attribute__((ext_vector_type(4))) float f32x4;

static __device__ __forceinline__ unsigned short f2bf(float f) {
  unsigned u = __float_as_uint(f);
  u += 0x7fff + ((u >> 16) & 1);   // round-to-nearest-even
  return (unsigned short)(u >> 16);
}
static __device__ __forceinline__ float bf2f(unsigned short h) {
  return __uint_as_float(((unsigned)h) << 16);
}

// async global->LDS, 16B per lane; LDS base must be wave-uniform (lane-linear fill)
static __device__ __forceinline__ void gload_lds16(const void* g, void* l) {
  __builtin_amdgcn_global_load_lds((const __attribute__((address_space(1))) unsigned*)g,
                                   (__attribute__((address_space(3))) unsigned*)l, 16, 0, 0);
}

// ---- pre-pass: W transpose-cast + cur zeroing (X-cast deleted: gemm reads X directly) ----
__global__ __launch_bounds__(256) void k_pre(const float* __restrict__ w,
                                             unsigned short* __restrict__ wt,
                                             int* __restrict__ cur) {
  int t = blockIdx.x * 256 + threadIdx.x;
  if (t < N_NODES) cur[t] = 0;
  int n = blockIdx.x >> 1;                          // wt row
  int k = ((blockIdx.x & 1) << 8) + threadIdx.x;    // coalesced write along wt row
  wt[n * D + k] = f2bf(w[k * D + n]);               // strided read; W is 1MB, L2-resident
}

// ---- fused: GEMM tiles first, edge-bucket fill last.
// GEMM reads fp32 X DIRECTLY via global_load_lds (async, 4 floats/lane), converts
// fp32->bf16 at fragment-read time (v_cvt_pk_bf16_f32, overlaps MFMA pipe).
// A: [128][64] f32 LDS (32KB), 16-slot XOR chunk-swizzle; B: [128][64] bf16 (16KB),
// 8-slot XOR swizzle; bijective XCD-chunked block swizzle. Pad rows clamped
// (C rows >= N_NODES are never consumed by k_agg).
__global__ __launch_bounds__(256) void k_gf(const float* __restrict__ X,
                                            const unsigned short* __restrict__ Bt,
                                            unsigned short* __restrict__ C,
                                            const float* __restrict__ ew,
                                            const int* __restrict__ esrc,
                                            const int* __restrict__ edst,
                                            int* __restrict__ cur,
                                            int2* __restrict__ cew) {
  __shared__ float          lds_af[128 * 64];  // 32 KB
  __shared__ unsigned short lds_b [128 * 64];  // 16 KB

  if (blockIdx.x >= GEMM_NB) {   // ---- fill blocks (dispatched after all gemm tiles)
    int e = (blockIdx.x - GEMM_NB) * 256 + threadIdx.x;   // e < 800000 exact
    int d = edst[e];
    int r = atomicAdd(&cur[d], 1);
    if (r < CAP) cew[(d << CAPSH) + r] = make_int2(esrc[e], __float_as_int(ew[e]));
    return;
  }

  // bijective chunked XCD swizzle (m204): 1564 = 8*195 + 4
  const int orig = blockIdx.x;
  const int q = GEMM_NB / 8, rq = GEMM_NB % 8;
  const int xcd = orig & 7, jj0 = orig >> 3;
  const int wgid = (xcd < rq ? xcd * (q + 1) : rq * (q + 1) + (xcd - rq) * q) + jj0;
  const int bm = wgid >> 2, bn = wgid & 3;

  const int tid  = threadIdx.x;
  const int m0   = bm * 128, n0 = bn * 128;
  const int wave = tid >> 6, lane = tid & 63;
  const int wm   = wave & 1, wn = wave >> 1;
  const int l15  = lane & 15, quad = lane >> 4;

  f32x4 acc[4][4];
#pragma unroll
  for (int i = 0; i < 4; i++)
#pragma unroll
    for (int j = 0; j < 4; j++) acc[i][j] = f32x4{0.f, 0.f, 0.f, 0.f};

  for (int kt = 0; kt < D / 64; ++kt) {        // 8 K-steps
    const int k0 = kt * 64;
    __syncthreads();
    // B: 1024 x 16B chunks (bf16), 8-slot XOR swizzle
#pragma unroll
    for (int c = 0; c < 4; c++) {
      int i = c * 256 + wave * 64 + lane;
      int r = i >> 3, s = i & 7;
      int g = s ^ (r & 7);
      gload_lds16(&Bt[(long long)(n0 + r) * D + k0 + (g << 3)], &lds_b[(c * 256 + wave * 64) * 8]);
    }
    // A: 2048 x 16B chunks (fp32!), 16-slot XOR swizzle, row-clamped source
#pragma unroll
    for (int c = 0; c < 8; c++) {
      int i = c * 256 + wave * 64 + lane;
      int r = i >> 4, s = i & 15;
      int g = s ^ (r & 15);
      int arow = m0 + r;
      arow = (arow < N_NODES) ? arow : (N_NODES - 1);   // pad rows: any valid data
      gload_lds16(&X[(long long)arow * D + k0 + (g << 2)], &lds_af[(c * 256 + wave * 64) * 4]);
    }
    __syncthreads();
#pragma unroll
    for (int kk = 0; kk < 2; kk++) {
      bf16x8 af[4], bfr[4];
#pragma unroll
      for (int t = 0; t < 4; t++) {
        int ra = wm * 64 + t * 16 + l15;
        int ma = ra & 15;
        int c0 = kk * 8 + quad * 2;              // first of two fp32 chunks (4 floats each)
        f32x4 lo = *(const f32x4*)&lds_af[ra * 64 + ((c0 ^ ma) << 2)];
        f32x4 hi = *(const f32x4*)&lds_af[ra * 64 + (((c0 + 1) ^ ma) << 2)];
        bf16x8 a;
        a[0] = (__bf16)lo[0]; a[1] = (__bf16)lo[1]; a[2] = (__bf16)lo[2]; a[3] = (__bf16)lo[3];
        a[4] = (__bf16)hi[0]; a[5] = (__bf16)hi[1]; a[6] = (__bf16)hi[2]; a[7] = (__bf16)hi[3];
        af[t] = a;
        int rb = wn * 64 + t * 16 + l15;
        bfr[t] = *(const bf16x8*)&lds_b[rb * 64 + ((((kk << 2) + quad) ^ (rb & 7)) << 3)];
      }
#pragma unroll
      for (int i = 0; i < 4; i++)
#pragma unroll
        for (int j = 0; j < 4; j++)
          acc[i][j] = __builtin_amdgcn_mfma_f32_16x16x32_bf16(af[i], bfr[j], acc[i][j], 0, 0, 0);
    }
  }

#pragma unroll
  for (int i = 0; i < 4; i++)
#pragma unroll
    for (int j = 0; j < 4; j++)
#pragma unroll
      for (int r = 0; r < 4; r++) {
        int row = m0 + wm * 64 + i * 16 + quad * 4 + r;
        int col = n0 + wn * 64 + j * 16 + l15;
        C[(long long)row * D + col] = f2bf(acc[i][j][r]);
      }
}

// ---- aggregate: one BLOCK per node, bucket CSR (pattern-bound at ~115 us) ----
__global__ __launch_bounds__(256) void k_agg(const int* __restrict__ cur,
                                             const int2* __restrict__ cew,
                                             const unsigned short* __restrict__ S,
                                             float* __restrict__ out) {
  __shared__ float s_part[4 * 512];
  const int node  = blockIdx.x;
  int cnt = cur[node];
  cnt = (cnt > CAP) ? CAP : cnt;             // memory-safety clamp (P(overflow)~1e-18)
  const int start = node << CAPSH, end = start + cnt;
  const int wave  = threadIdx.x >> 6, lane = threadIdx.x & 63;
  float a[8];
#pragma unroll
  for (int k = 0; k < 8; k++) a[k] = 0.f;

#define EDGE_FMA(V, W)                                             \
  do {                                                             \
    a[0] = fmaf(W, bf2f((unsigned short)(V.x & 0xffffu)), a[0]);   \
    a[1] = fmaf(W, bf2f((unsigned short)(V.x >> 16)),     a[1]);   \
    a[2] = fmaf(W, bf2f((unsigned short)(V.y & 0xffffu)), a[2]);   \
    a[3] = fmaf(W, bf2f((unsigned short)(V.y >> 16)),     a[3]);   \
    a[4] = fmaf(W, bf2f((unsigned short)(V.z & 0xffffu)), a[4]);   \
    a[5] = fmaf(W, bf2f((unsigned short)(V.z >> 16)),     a[5]);   \
    a[6] = fmaf(W, bf2f((unsigned short)(V.w & 0xffffu)), a[6]);   \
    a[7] = fmaf(W, bf2f((unsigned short)(V.w >> 16)),     a[7]);   \
  } while (0)

#define GATHER(P) (*(const uint4*)(S + (size_t)(P).x * D + lane * 8))

  int e = start + wave;
  // 2-deep pipelined pairs across 4 waves (8 rows in flight per block)
  for (; e + 4 < end; e += 8) {
    int2 p0 = cew[e], p1 = cew[e + 4];
    uint4 v0 = GATHER(p0);
    uint4 v1 = GATHER(p1);
    EDGE_FMA(v0, __int_as_float(p0.y));
    EDGE_FMA(v1, __int_as_float(p1.y));
  }
  if (e < end) {
    int2 p0 = cew[e];
    uint4 v0 = GATHER(p0);
    EDGE_FMA(v0, __int_as_float(p0.y));
  }
#undef GATHER
#undef EDGE_FMA

  // cross-wave combine
  float4* sp = (float4*)&s_part[wave * 512 + lane * 8];
  sp[0] = make_float4(a[0], a[1], a[2], a[3]);
  sp[1] = make_float4(a[4], a[5], a[6], a[7]);
  __syncthreads();
  int col = threadIdx.x * 2;
  float2 r0 = *(const float2*)&s_part[0 * 512 + col];
  float2 r1 = *(const float2*)&s_part[1 * 512 + col];
  float2 r2 = *(const float2*)&s_part[2 * 512 + col];
  float2 r3 = *(const float2*)&s_part[3 * 512 + col];
  float2 res = make_float2(r0.x + r1.x + r2.x + r3.x, r0.y + r1.y + r2.y + r3.y);
  // non-temporal 8B store (out never re-read; keep L2/L3 for S)
  typedef __attribute__((ext_vector_type(2))) float f32x2;
  f32x2 rv = {res.x, res.y};
  __builtin_nontemporal_store(rv, (f32x2*)(out + (size_t)node * D + col));
}

extern "C" void kernel_launch(void* const* d_in, const int* in_sizes, int n_in,
                              void* d_out, int out_size, void* d_ws, size_t ws_size,
                              hipStream_t stream) {
  const float* x    = (const float*)d_in[0];
  const float* w    = (const float*)d_in[1];
  const float* ew   = (const float*)d_in[2];
  const int*   esrc = (const int*)d_in[3];
  const int*   edst = (const int*)d_in[4];
  float* out = (float*)d_out;

  char* p = (char*)d_ws;
  auto align256 = [](size_t v) { return (v + 255) & ~(size_t)255; };
  unsigned short* sb = (unsigned short*)p;  p += align256((size_t)M_PAD * D * 2);
  unsigned short* wt = (unsigned short*)p;  p += align256((size_t)D * D * 2);
  int*   cur  = (int*)p;   p += align256((size_t)N_NODES * 4);
  int2*  cew  = (int2*)p;  p += align256((size_t)N_NODES * CAP * 8);

  // pre-pass: W^T cast + cur zeroing (3 dispatches total)
  k_pre<<<WT_NB, 256, 0, stream>>>(w, wt, cur);
  // fused: GEMM (fp32 X direct, fused cast) first, fill blocks last
  k_gf<<<GEMM_NB + FILL_NB, 256, 0, stream>>>(x, wt, sb, ew, esrc, edst, cur, cew);
  // aggregate: one block per node, fixed-capacity bucket CSR
  k_agg<<<N_NODES, 256, 0, stream>>>(cur, cew, sb, out);
}